// Round 1
// baseline (404.129 us; speedup 1.0000x reference)
//
#include <hip/hip_runtime.h>

// NRI MLP decoder, fp32 baseline.
// Shapes: B=8, N=64, T=50 (49 used), D=4, H=64, K=2 (only i=1 active), E=4032.
// One 64-thread block per (b,t,n): computes agg[b,t,n,:] over all senders s,
// then the 3-layer node MLP, writes 4 floats. No LDS, no barriers, no ws.

#define NB 8
#define NN 64
#define NT 50
#define NTO 49
#define ND 4
#define NH 64
#define NE 4032

__device__ __forceinline__ float rl(float v, int k) {
  // broadcast lane k's value (VALU v_readlane -> SGPR operand for fma)
  return __builtin_bit_cast(float, __builtin_amdgcn_readlane(__builtin_bit_cast(int, v), k));
}

__global__ __launch_bounds__(64) void nri_decoder_kernel(
    const float* __restrict__ inputs,   // (B,N,T,D)
    const float* __restrict__ rel_type, // (B,1,E,K)
    const float* __restrict__ fc1_w,    // (K,H,2D)
    const float* __restrict__ fc1_b,    // (K,H)
    const float* __restrict__ fc2_w,    // (K,H,H)
    const float* __restrict__ fc2_b,    // (K,H)
    const float* __restrict__ out1_w,   // (H, D+H)=（64,68)
    const float* __restrict__ out1_b,   // (H)
    const float* __restrict__ out2_w,   // (H,H)
    const float* __restrict__ out2_b,   // (H)
    const float* __restrict__ out3_w,   // (D,H)
    const float* __restrict__ out3_b,   // (D)
    float* __restrict__ out)            // (B,N,49,D)
{
  const int bid  = blockIdx.x;
  const int n    = bid & 63;
  const int t    = (bid >> 6) % NTO;
  const int b    = bid / (NTO * NN);
  const int lane = threadIdx.x;

  // --- per-lane fc1 weight rows (relation i=1): fc1_w[1][h=lane][0..7]
  float w1r[4], w1s[4];
  *(float4*)w1r = *(const float4*)(fc1_w + 512 + lane * 8);      // recv part d=0..3
  *(float4*)w1s = *(const float4*)(fc1_w + 512 + lane * 8 + 4);  // send part d=0..3

  // --- per-lane fc2 weight row: fc2_w[1][o=lane][k], k=0..63
  float w2[64];
  {
    const float4* p = (const float4*)(fc2_w + 4096 + lane * 64);
#pragma unroll
    for (int c = 0; c < 16; ++c) ((float4*)w2)[c] = p[c];
  }
  const float b1l = fc1_b[64 + lane];
  const float b2l = fc2_b[64 + lane];

  // --- x_n = x_in[b,t,n,:] = inputs[b,n,t,:]  (uniform across lanes)
  const float4 xn = *(const float4*)(inputs + ((b * NN + n) * NT + t) * ND);

  // ub[k=lane] = u[n][k] + b1[k]  (recv half of fc1 + bias)
  const float ubl = b1l + w1r[0] * xn.x + w1r[1] * xn.y + w1r[2] * xn.z + w1r[3] * xn.w;

  // --- edge loop over senders s: agg[n][o=lane] = sum_s rt * relu(fc2(relu(ub+v_s))+b2)
  float agg = 0.f;
  for (int s = 0; s < NN; ++s) {
    if (s == n) continue;  // uniform branch: no self edge
    const int j = (s < n) ? s : s - 1;
    const float rt = rel_type[(b * NE + n * 63 + j) * 2 + 1];  // [...,i=1]

    const float4 xs = *(const float4*)(inputs + ((b * NN + s) * NT + t) * ND);
    // h[s][k=lane] = relu(ub[k] + v_s[k])
    float hv = ubl + w1s[0] * xs.x + w1s[1] * xs.y + w1s[2] * xs.z + w1s[3] * xs.w;
    hv = fmaxf(hv, 0.f);

    // m[s][o=lane] = sum_k h[s][k] * W2[o][k]
    float m0 = 0.f, m1 = 0.f, m2 = 0.f, m3 = 0.f;
#pragma unroll
    for (int k = 0; k < 64; k += 4) {
      m0 = fmaf(rl(hv, k + 0), w2[k + 0], m0);
      m1 = fmaf(rl(hv, k + 1), w2[k + 1], m1);
      m2 = fmaf(rl(hv, k + 2), w2[k + 2], m2);
      m3 = fmaf(rl(hv, k + 3), w2[k + 3], m3);
    }
    const float m = fmaxf(b2l + ((m0 + m1) + (m2 + m3)), 0.f);
    agg = fmaf(rt, m, agg);
  }

  // --- node MLP: aug = [x_n(4), agg(64)] -> h1(64) -> h2(64) -> delta(4)
  float h1;
  {
    float o1w[68];
    const float4* p = (const float4*)(out1_w + lane * 68);
#pragma unroll
    for (int c = 0; c < 17; ++c) ((float4*)o1w)[c] = p[c];
    float a0 = out1_b[lane] + o1w[0] * xn.x + o1w[1] * xn.y + o1w[2] * xn.z + o1w[3] * xn.w;
    float a1 = 0.f, a2 = 0.f, a3 = 0.f;
#pragma unroll
    for (int j2 = 0; j2 < 64; j2 += 4) {
      a0 = fmaf(rl(agg, j2 + 0), o1w[4 + j2 + 0], a0);
      a1 = fmaf(rl(agg, j2 + 1), o1w[4 + j2 + 1], a1);
      a2 = fmaf(rl(agg, j2 + 2), o1w[4 + j2 + 2], a2);
      a3 = fmaf(rl(agg, j2 + 3), o1w[4 + j2 + 3], a3);
    }
    h1 = fmaxf((a0 + a1) + (a2 + a3), 0.f);
  }

  float h2;
  {
    float o2w[64];
    const float4* p = (const float4*)(out2_w + lane * 64);
#pragma unroll
    for (int c = 0; c < 16; ++c) ((float4*)o2w)[c] = p[c];
    float a0 = out2_b[lane], a1 = 0.f, a2 = 0.f, a3 = 0.f;
#pragma unroll
    for (int j2 = 0; j2 < 64; j2 += 4) {
      a0 = fmaf(rl(h1, j2 + 0), o2w[j2 + 0], a0);
      a1 = fmaf(rl(h1, j2 + 1), o2w[j2 + 1], a1);
      a2 = fmaf(rl(h1, j2 + 2), o2w[j2 + 2], a2);
      a3 = fmaf(rl(h1, j2 + 3), o2w[j2 + 3], a3);
    }
    h2 = fmaxf((a0 + a1) + (a2 + a3), 0.f);
  }

  // delta[d=lane&3] (computed redundantly by 16 lanes; lanes 0..3 store)
  {
    const int d = lane & 3;
    float o3w[64];
    const float4* p = (const float4*)(out3_w + d * 64);
#pragma unroll
    for (int c = 0; c < 16; ++c) ((float4*)o3w)[c] = p[c];
    float a0 = out3_b[d], a1 = 0.f, a2 = 0.f, a3 = 0.f;
#pragma unroll
    for (int j2 = 0; j2 < 64; j2 += 4) {
      a0 = fmaf(rl(h2, j2 + 0), o3w[j2 + 0], a0);
      a1 = fmaf(rl(h2, j2 + 1), o3w[j2 + 1], a1);
      a2 = fmaf(rl(h2, j2 + 2), o3w[j2 + 2], a2);
      a3 = fmaf(rl(h2, j2 + 3), o3w[j2 + 3], a3);
    }
    const float delta = (a0 + a1) + (a2 + a3);
    const float xd = (d == 0) ? xn.x : (d == 1) ? xn.y : (d == 2) ? xn.z : xn.w;
    if (lane < 4) {
      out[((b * NN + n) * NTO + t) * ND + d] = xd + delta;
    }
  }
}

extern "C" void kernel_launch(void* const* d_in, const int* in_sizes, int n_in,
                              void* d_out, int out_size, void* d_ws, size_t ws_size,
                              hipStream_t stream) {
  const float* inputs   = (const float*)d_in[0];
  const float* rel_type = (const float*)d_in[1];
  // d_in[2]=rel_rec, d_in[3]=rel_send: one-hot, implicit in edge enumeration
  const float* fc1_w  = (const float*)d_in[4];
  const float* fc1_b  = (const float*)d_in[5];
  const float* fc2_w  = (const float*)d_in[6];
  const float* fc2_b  = (const float*)d_in[7];
  const float* out1_w = (const float*)d_in[8];
  const float* out1_b = (const float*)d_in[9];
  const float* out2_w = (const float*)d_in[10];
  const float* out2_b = (const float*)d_in[11];
  const float* out3_w = (const float*)d_in[12];
  const float* out3_b = (const float*)d_in[13];
  float* out = (float*)d_out;

  const int nblocks = NB * NTO * NN;  // 8*49*64 = 25088
  nri_decoder_kernel<<<nblocks, 64, 0, stream>>>(
      inputs, rel_type, fc1_w, fc1_b, fc2_w, fc2_b,
      out1_w, out1_b, out2_w, out2_b, out3_w, out3_b, out);
}

// Round 2
// 219.691 us; speedup vs baseline: 1.8395x; 1.8395x over previous
//
#include <hip/hip_runtime.h>

// NRI MLP decoder, round 2: MFMA edge kernel + scalar node kernel.
// B=8, N=64, T=50 (49 used), D=4, H=64, K=2 (only relation i=1), E=4032.
//
// Edge math: h[n,s,k] = relu(U[n][k] + V[s][k] + b1[k]) where U = X W1r^T,
// V = X W1s^T; m = relu(h W2^T + b2); agg[n][o] = sum_s rt[n,s] m[n,s][o].
// fc2 GEMM (13.2 of 13.6 GFLOP) runs on mfma_f32_16x16x32_bf16; everything
// else fp32. agg staged in d_ws (8*49*64*64 f32 = 6.4 MB).

#define NB 8
#define NN 64
#define NT 50
#define NTO 49
#define ND 4
#define NH 64
#define NE 4032

typedef short bf16x8 __attribute__((ext_vector_type(8)));   // 8 bf16 in 4 VGPRs
typedef float f32x4 __attribute__((ext_vector_type(4)));
typedef unsigned u32x4 __attribute__((ext_vector_type(4)));

// pack two f32 -> two bf16 (round-half-up) in one dword via v_perm
__device__ __forceinline__ unsigned pkbf(float lo, float hi) {
  const unsigned ul = __builtin_bit_cast(unsigned, lo) + 0x8000u;
  const unsigned uh = __builtin_bit_cast(unsigned, hi) + 0x8000u;
  return __builtin_amdgcn_perm(uh, ul, 0x07060302u);  // {lo.hi16, hi.hi16}
}

__device__ __forceinline__ float rl(float v, int k) {
  return __builtin_bit_cast(float, __builtin_amdgcn_readlane(__builtin_bit_cast(int, v), k));
}

// ---------------------------------------------------------------------------
// Edge kernel: grid = B*49*4 blocks, 256 threads (4 waves).
// Block handles (b, t, 16 receivers n_base..n_base+15); wave handles 4 of them.
// ---------------------------------------------------------------------------
__global__ __launch_bounds__(256) void nri_edge_kernel(
    const float* __restrict__ inputs,   // (B,N,T,D)
    const float* __restrict__ rel_type, // (B,1,E,2)
    const float* __restrict__ fc1_w,    // (2,64,8)
    const float* __restrict__ fc1_b,    // (2,64)
    const float* __restrict__ fc2_w,    // (2,64,64)
    const float* __restrict__ fc2_b,    // (2,64)
    float* __restrict__ aggws)          // (B,49,64,64) f32
{
  __shared__ float Vl[NN * 68];   // V[s][k], stride 68: b128 reads at bank floor
  __shared__ float Pl[16 * 68];   // U[n][k]+b1[k] for block's 16 receivers
  __shared__ float Rl[16 * NN];   // rt[n][s], self-edge = 0

  const int bid   = blockIdx.x;
  const int tile  = bid & 3;
  const int t     = (bid >> 2) % NTO;
  const int b     = bid / (4 * NTO);
  const int n_base = tile * 16;
  const int tid  = threadIdx.x;
  const int lane = tid & 63;
  const int w    = tid >> 6;
  const int q    = lane >> 4;   // quad 0..3
  const int r    = lane & 15;

  // ---- stage fc1 outputs: lane = k, waves split rows
  {
    const int k = lane;
    const float4 w1r = *(const float4*)(fc1_w + 512 + k * 8);
    const float4 w1s = *(const float4*)(fc1_w + 512 + k * 8 + 4);
    const float b1k  = fc1_b[64 + k];
    for (int i = w; i < NN; i += 4) {
      const float4 x = *(const float4*)(inputs + ((b * NN + i) * NT + t) * ND);
      Vl[i * 68 + k] = w1s.x * x.x + w1s.y * x.y + w1s.z * x.z + w1s.w * x.w;
    }
    for (int i = w; i < 16; i += 4) {
      const int n = n_base + i;
      const float4 x = *(const float4*)(inputs + ((b * NN + n) * NT + t) * ND);
      Pl[i * 68 + k] = b1k + w1r.x * x.x + w1r.y * x.y + w1r.z * x.z + w1r.w * x.w;
    }
  }
  // ---- stage rt (1024 entries)
  for (int idx = tid; idx < 16 * NN; idx += 256) {
    const int i = idx >> 6, s = idx & 63;
    const int n = n_base + i;
    float v = 0.f;
    if (s != n) v = rel_type[(b * NE + n * 63 + (s < n ? s : s - 1)) * 2 + 1];
    Rl[idx] = v;
  }

  // ---- preload W2^T B-fragments (relation 1), held in VGPRs for the kernel.
  // B-frag[nt][ks]: lane holds B[k = ks*32 + q*8 + j][o = nt*16 + r], j=0..7
  bf16x8 bfr[4][2];
  float b2l[4];
#pragma unroll
  for (int nt = 0; nt < 4; ++nt) {
    const int o = nt * 16 + r;
    b2l[nt] = fc2_b[64 + o];
#pragma unroll
    for (int ks = 0; ks < 2; ++ks) {
      const float* p = fc2_w + 4096 + o * 64 + ks * 32 + q * 8;
      const float4 c0 = *(const float4*)p;
      const float4 c1 = *(const float4*)(p + 4);
      u32x4 u;
      u.x = pkbf(c0.x, c0.y); u.y = pkbf(c0.z, c0.w);
      u.z = pkbf(c1.x, c1.y); u.w = pkbf(c1.z, c1.w);
      bfr[nt][ks] = __builtin_bit_cast(bf16x8, u);
    }
  }
  __syncthreads();

  // ---- main loop: wave's 4 receivers × 4 sender-tiles of 16
#pragma unroll
  for (int np = 0; np < 4; ++np) {
    const int ni = w * 4 + np;         // receiver within block tile
    const int n  = n_base + ni;
    // P row fragment: k = ks*32 + q*8 + j (uniform over r -> LDS broadcast)
    float pn[16];
    *(float4*)(pn +  0) = *(const float4*)(Pl + ni * 68 + q * 8);
    *(float4*)(pn +  4) = *(const float4*)(Pl + ni * 68 + q * 8 + 4);
    *(float4*)(pn +  8) = *(const float4*)(Pl + ni * 68 + 32 + q * 8);
    *(float4*)(pn + 12) = *(const float4*)(Pl + ni * 68 + 32 + q * 8 + 4);

    float ag0 = 0.f, ag1 = 0.f, ag2 = 0.f, ag3 = 0.f;  // per N-tile partials
#pragma unroll
    for (int st = 0; st < 4; ++st) {
      const int s = st * 16 + r;       // A-row sender
      float vv[16];
      *(float4*)(vv +  0) = *(const float4*)(Vl + s * 68 + q * 8);
      *(float4*)(vv +  4) = *(const float4*)(Vl + s * 68 + q * 8 + 4);
      *(float4*)(vv +  8) = *(const float4*)(Vl + s * 68 + 32 + q * 8);
      *(float4*)(vv + 12) = *(const float4*)(Vl + s * 68 + 32 + q * 8 + 4);
      float h[16];
#pragma unroll
      for (int j = 0; j < 16; ++j) h[j] = fmaxf(pn[j] + vv[j], 0.f);
      u32x4 a0u, a1u;
      a0u.x = pkbf(h[0], h[1]);   a0u.y = pkbf(h[2], h[3]);
      a0u.z = pkbf(h[4], h[5]);   a0u.w = pkbf(h[6], h[7]);
      a1u.x = pkbf(h[8], h[9]);   a1u.y = pkbf(h[10], h[11]);
      a1u.z = pkbf(h[12], h[13]); a1u.w = pkbf(h[14], h[15]);
      const bf16x8 a0 = __builtin_bit_cast(bf16x8, a0u);  // k 0..31
      const bf16x8 a1 = __builtin_bit_cast(bf16x8, a1u);  // k 32..63

      f32x4 d0 = {0.f,0.f,0.f,0.f}, d1 = {0.f,0.f,0.f,0.f};
      f32x4 d2 = {0.f,0.f,0.f,0.f}, d3 = {0.f,0.f,0.f,0.f};
      d0 = __builtin_amdgcn_mfma_f32_16x16x32_bf16(a0, bfr[0][0], d0, 0, 0, 0);
      d0 = __builtin_amdgcn_mfma_f32_16x16x32_bf16(a1, bfr[0][1], d0, 0, 0, 0);
      d1 = __builtin_amdgcn_mfma_f32_16x16x32_bf16(a0, bfr[1][0], d1, 0, 0, 0);
      d1 = __builtin_amdgcn_mfma_f32_16x16x32_bf16(a1, bfr[1][1], d1, 0, 0, 0);
      d2 = __builtin_amdgcn_mfma_f32_16x16x32_bf16(a0, bfr[2][0], d2, 0, 0, 0);
      d2 = __builtin_amdgcn_mfma_f32_16x16x32_bf16(a1, bfr[2][1], d2, 0, 0, 0);
      d3 = __builtin_amdgcn_mfma_f32_16x16x32_bf16(a0, bfr[3][0], d3, 0, 0, 0);
      d3 = __builtin_amdgcn_mfma_f32_16x16x32_bf16(a1, bfr[3][1], d3, 0, 0, 0);

      // D rows = senders st*16 + q*4 + reg; rt for those 4 rows:
      const float4 rt4 = *(const float4*)(Rl + ni * NN + st * 16 + q * 4);
      ag0 += rt4.x * fmaxf(d0[0] + b2l[0], 0.f) + rt4.y * fmaxf(d0[1] + b2l[0], 0.f)
           + rt4.z * fmaxf(d0[2] + b2l[0], 0.f) + rt4.w * fmaxf(d0[3] + b2l[0], 0.f);
      ag1 += rt4.x * fmaxf(d1[0] + b2l[1], 0.f) + rt4.y * fmaxf(d1[1] + b2l[1], 0.f)
           + rt4.z * fmaxf(d1[2] + b2l[1], 0.f) + rt4.w * fmaxf(d1[3] + b2l[1], 0.f);
      ag2 += rt4.x * fmaxf(d2[0] + b2l[2], 0.f) + rt4.y * fmaxf(d2[1] + b2l[2], 0.f)
           + rt4.z * fmaxf(d2[2] + b2l[2], 0.f) + rt4.w * fmaxf(d2[3] + b2l[2], 0.f);
      ag3 += rt4.x * fmaxf(d3[0] + b2l[3], 0.f) + rt4.y * fmaxf(d3[1] + b2l[3], 0.f)
           + rt4.z * fmaxf(d3[2] + b2l[3], 0.f) + rt4.w * fmaxf(d3[3] + b2l[3], 0.f);
    }
    // reduce over quads (each quad summed 16 of the 64 senders)
    ag0 += __shfl_xor(ag0, 16); ag0 += __shfl_xor(ag0, 32);
    ag1 += __shfl_xor(ag1, 16); ag1 += __shfl_xor(ag1, 32);
    ag2 += __shfl_xor(ag2, 16); ag2 += __shfl_xor(ag2, 32);
    ag3 += __shfl_xor(ag3, 16); ag3 += __shfl_xor(ag3, 32);
    const float val = (q == 0) ? ag0 : (q == 1) ? ag1 : (q == 2) ? ag2 : ag3;
    aggws[((b * NTO + t) * NN + n) * NH + q * 16 + r] = val;
  }
}

// ---------------------------------------------------------------------------
// Node kernel: grid = B*49*64 blocks, 64 threads. Round-1 structure, agg from ws.
// ---------------------------------------------------------------------------
__global__ __launch_bounds__(64) void nri_node_kernel(
    const float* __restrict__ inputs,
    const float* __restrict__ out1_w, const float* __restrict__ out1_b,
    const float* __restrict__ out2_w, const float* __restrict__ out2_b,
    const float* __restrict__ out3_w, const float* __restrict__ out3_b,
    const float* __restrict__ aggws,
    float* __restrict__ out)
{
  const int bid  = blockIdx.x;
  const int n    = bid & 63;
  const int t    = (bid >> 6) % NTO;
  const int b    = bid / (NTO * NN);
  const int lane = threadIdx.x;

  const float4 xn = *(const float4*)(inputs + ((b * NN + n) * NT + t) * ND);
  const float agg = aggws[((b * NTO + t) * NN + n) * NH + lane];

  float h1;
  {
    float o1w[68];
    const float4* p = (const float4*)(out1_w + lane * 68);
#pragma unroll
    for (int c = 0; c < 17; ++c) ((float4*)o1w)[c] = p[c];
    float a0 = out1_b[lane] + o1w[0] * xn.x + o1w[1] * xn.y + o1w[2] * xn.z + o1w[3] * xn.w;
    float a1 = 0.f, a2 = 0.f, a3 = 0.f;
#pragma unroll
    for (int j2 = 0; j2 < 64; j2 += 4) {
      a0 = fmaf(rl(agg, j2 + 0), o1w[4 + j2 + 0], a0);
      a1 = fmaf(rl(agg, j2 + 1), o1w[4 + j2 + 1], a1);
      a2 = fmaf(rl(agg, j2 + 2), o1w[4 + j2 + 2], a2);
      a3 = fmaf(rl(agg, j2 + 3), o1w[4 + j2 + 3], a3);
    }
    h1 = fmaxf((a0 + a1) + (a2 + a3), 0.f);
  }

  float h2;
  {
    float o2w[64];
    const float4* p = (const float4*)(out2_w + lane * 64);
#pragma unroll
    for (int c = 0; c < 16; ++c) ((float4*)o2w)[c] = p[c];
    float a0 = out2_b[lane], a1 = 0.f, a2 = 0.f, a3 = 0.f;
#pragma unroll
    for (int j2 = 0; j2 < 64; j2 += 4) {
      a0 = fmaf(rl(h1, j2 + 0), o2w[j2 + 0], a0);
      a1 = fmaf(rl(h1, j2 + 1), o2w[j2 + 1], a1);
      a2 = fmaf(rl(h1, j2 + 2), o2w[j2 + 2], a2);
      a3 = fmaf(rl(h1, j2 + 3), o2w[j2 + 3], a3);
    }
    h2 = fmaxf((a0 + a1) + (a2 + a3), 0.f);
  }

  {
    const int d = lane & 3;
    float o3w[64];
    const float4* p = (const float4*)(out3_w + d * 64);
#pragma unroll
    for (int c = 0; c < 16; ++c) ((float4*)o3w)[c] = p[c];
    float a0 = out3_b[d], a1 = 0.f, a2 = 0.f, a3 = 0.f;
#pragma unroll
    for (int j2 = 0; j2 < 64; j2 += 4) {
      a0 = fmaf(rl(h2, j2 + 0), o3w[j2 + 0], a0);
      a1 = fmaf(rl(h2, j2 + 1), o3w[j2 + 1], a1);
      a2 = fmaf(rl(h2, j2 + 2), o3w[j2 + 2], a2);
      a3 = fmaf(rl(h2, j2 + 3), o3w[j2 + 3], a3);
    }
    const float delta = (a0 + a1) + (a2 + a3);
    const float xd = (d == 0) ? xn.x : (d == 1) ? xn.y : (d == 2) ? xn.z : xn.w;
    if (lane < 4) {
      out[((b * NN + n) * NTO + t) * ND + d] = xd + delta;
    }
  }
}

extern "C" void kernel_launch(void* const* d_in, const int* in_sizes, int n_in,
                              void* d_out, int out_size, void* d_ws, size_t ws_size,
                              hipStream_t stream) {
  const float* inputs   = (const float*)d_in[0];
  const float* rel_type = (const float*)d_in[1];
  const float* fc1_w  = (const float*)d_in[4];
  const float* fc1_b  = (const float*)d_in[5];
  const float* fc2_w  = (const float*)d_in[6];
  const float* fc2_b  = (const float*)d_in[7];
  const float* out1_w = (const float*)d_in[8];
  const float* out1_b = (const float*)d_in[9];
  const float* out2_w = (const float*)d_in[10];
  const float* out2_b = (const float*)d_in[11];
  const float* out3_w = (const float*)d_in[12];
  const float* out3_b = (const float*)d_in[13];
  float* out = (float*)d_out;
  float* aggws = (float*)d_ws;  // 8*49*64*64 f32 = 6.4 MB

  nri_edge_kernel<<<NB * NTO * 4, 256, 0, stream>>>(
      inputs, rel_type, fc1_w, fc1_b, fc2_w, fc2_b, aggws);
  nri_node_kernel<<<NB * NTO * NN, 64, 0, stream>>>(
      inputs, out1_w, out1_b, out2_w, out2_b, out3_w, out3_b, aggws, out);
}

// Round 3
// 129.623 us; speedup vs baseline: 3.1177x; 1.6948x over previous
//
#include <hip/hip_runtime.h>

// NRI MLP decoder, round 3: single fused kernel.
// B=8, N=64, T=50 (49 used), D=4, H=64, K=2 (only relation i=1), E=4032.
// Block = (b, t, 16-receiver tile), 256 threads (4 waves).
// Phase 1 (edge): h = relu(U[n]+V[s]+b1); m = relu(h W2^T + b2) via
//   mfma_f32_16x16x32_f16; agg[n][o] = sum_s rt[n,s] m.  (13.2 GFLOP)
// Phase 2 (node): 3-layer MLP on the 16 rows via the same MFMA shape,
//   activations round-trip through LDS (C-layout -> A-layout).
// All accumulation fp32; MFMA inputs f16 (v_cvt_pkrtz).

#define NB 8
#define NN 64
#define NT 50
#define NTO 49
#define ND 4
#define NH 64
#define NE 4032

typedef _Float16 f16x8 __attribute__((ext_vector_type(8)));
typedef float f32x4 __attribute__((ext_vector_type(4)));

union Frag { unsigned u[4]; f16x8 f; };

__device__ __forceinline__ unsigned pk16(float lo, float hi) {
  // v_cvt_pkrtz_f16_f32: lo -> low16, hi -> high16
  return __builtin_bit_cast(unsigned, __builtin_amdgcn_cvt_pkrtz(lo, hi));
}

#define MFMA16(A, B, C) __builtin_amdgcn_mfma_f32_16x16x32_f16((A), (B), (C), 0, 0, 0)

__global__ __launch_bounds__(256) void nri_fused_kernel(
    const float* __restrict__ inputs,   // (B,N,T,D)
    const float* __restrict__ rel_type, // (B,1,E,2)
    const float* __restrict__ fc1_w,    // (2,64,8)
    const float* __restrict__ fc1_b,    // (2,64)
    const float* __restrict__ fc2_w,    // (2,64,64)
    const float* __restrict__ fc2_b,    // (2,64)
    const float* __restrict__ out1_w,   // (64,68)
    const float* __restrict__ out1_b,   // (64)
    const float* __restrict__ out2_w,   // (64,64)
    const float* __restrict__ out2_b,   // (64)
    const float* __restrict__ out3_w,   // (4,64)
    const float* __restrict__ out3_b,   // (4)
    float* __restrict__ out)            // (B,N,49,4)
{
  __shared__ float  Vl[NN * 68];   // V[s][k]
  __shared__ float  Pl[16 * 68];   // U[n][k]+b1[k]
  __shared__ float  Rl[16 * NN];   // rt[n][s]
  __shared__ float4 Xl[16];        // x_in rows for block receivers
  __shared__ float  AggL[16 * 68]; // agg[n][o]
  __shared__ float  H1L[16 * 68];
  __shared__ float  H2L[16 * 68];

  const int bid    = blockIdx.x;
  const int tile   = bid & 3;
  const int t      = (bid >> 2) % NTO;
  const int b      = bid / (4 * NTO);
  const int n_base = tile * 16;
  const int tid  = threadIdx.x;
  const int lane = tid & 63;
  const int w    = tid >> 6;
  const int q    = lane >> 4;
  const int r    = lane & 15;

  // ---------------- staging ----------------
  {
    const int k = lane;
    const float4 w1r = *(const float4*)(fc1_w + 512 + k * 8);
    const float4 w1s = *(const float4*)(fc1_w + 516 + k * 8);
    const float  b1k = fc1_b[64 + k];
    for (int i = w; i < NN; i += 4) {
      const float4 x = *(const float4*)(inputs + ((b * NN + i) * NT + t) * ND);
      Vl[i * 68 + k] = w1s.x * x.x + w1s.y * x.y + w1s.z * x.z + w1s.w * x.w;
    }
    for (int i = w; i < 16; i += 4) {
      const float4 x = *(const float4*)(inputs + ((b * NN + n_base + i) * NT + t) * ND);
      Pl[i * 68 + k] = b1k + w1r.x * x.x + w1r.y * x.y + w1r.z * x.z + w1r.w * x.w;
    }
  }
  for (int idx = tid; idx < 16 * NN; idx += 256) {
    const int i = idx >> 6, s = idx & 63;
    const int n = n_base + i;
    Rl[idx] = (s == n) ? 0.f
                       : rel_type[(b * NE + n * 63 + (s < n ? s : s - 1)) * 2 + 1];
  }
  if (tid < 16)
    Xl[tid] = *(const float4*)(inputs + ((b * NN + n_base + tid) * NT + t) * ND);

  // ---- W2 (relation 1) -> f16 B-frags, held in VGPRs
  Frag bfr[4][2];
  float b2l[4];
#pragma unroll
  for (int nt = 0; nt < 4; ++nt) {
    const int o = nt * 16 + r;
    b2l[nt] = fc2_b[64 + o];
#pragma unroll
    for (int ks = 0; ks < 2; ++ks) {
      const float* p = fc2_w + 4096 + o * 64 + ks * 32 + q * 8;
      const float4 c0 = *(const float4*)p;
      const float4 c1 = *(const float4*)(p + 4);
      bfr[nt][ks].u[0] = pk16(c0.x, c0.y);
      bfr[nt][ks].u[1] = pk16(c0.z, c0.w);
      bfr[nt][ks].u[2] = pk16(c1.x, c1.y);
      bfr[nt][ks].u[3] = pk16(c1.z, c1.w);
    }
  }
  __syncthreads();

  // ---------------- edge phase ----------------
#pragma unroll 1
  for (int np = 0; np < 4; ++np) {
    const int ni = w * 4 + np;
    float pn[16];
    *(float4*)(pn + 0)  = *(const float4*)(Pl + ni * 68 + q * 8);
    *(float4*)(pn + 4)  = *(const float4*)(Pl + ni * 68 + q * 8 + 4);
    *(float4*)(pn + 8)  = *(const float4*)(Pl + ni * 68 + 32 + q * 8);
    *(float4*)(pn + 12) = *(const float4*)(Pl + ni * 68 + 36 + q * 8);

    float ag0 = 0.f, ag1 = 0.f, ag2 = 0.f, ag3 = 0.f;
#pragma unroll
    for (int st = 0; st < 4; ++st) {
      const int s = st * 16 + r;
      float vv[16];
      *(float4*)(vv + 0)  = *(const float4*)(Vl + s * 68 + q * 8);
      *(float4*)(vv + 4)  = *(const float4*)(Vl + s * 68 + q * 8 + 4);
      *(float4*)(vv + 8)  = *(const float4*)(Vl + s * 68 + 32 + q * 8);
      *(float4*)(vv + 12) = *(const float4*)(Vl + s * 68 + 36 + q * 8);
      float h[16];
#pragma unroll
      for (int j = 0; j < 16; ++j) h[j] = fmaxf(pn[j] + vv[j], 0.f);
      Frag a0, a1;
      a0.u[0] = pk16(h[0],  h[1]);  a0.u[1] = pk16(h[2],  h[3]);
      a0.u[2] = pk16(h[4],  h[5]);  a0.u[3] = pk16(h[6],  h[7]);
      a1.u[0] = pk16(h[8],  h[9]);  a1.u[1] = pk16(h[10], h[11]);
      a1.u[2] = pk16(h[12], h[13]); a1.u[3] = pk16(h[14], h[15]);

      f32x4 d0 = {b2l[0], b2l[0], b2l[0], b2l[0]};
      f32x4 d1 = {b2l[1], b2l[1], b2l[1], b2l[1]};
      f32x4 d2 = {b2l[2], b2l[2], b2l[2], b2l[2]};
      f32x4 d3 = {b2l[3], b2l[3], b2l[3], b2l[3]};
      d0 = MFMA16(a0.f, bfr[0][0].f, d0); d0 = MFMA16(a1.f, bfr[0][1].f, d0);
      d1 = MFMA16(a0.f, bfr[1][0].f, d1); d1 = MFMA16(a1.f, bfr[1][1].f, d1);
      d2 = MFMA16(a0.f, bfr[2][0].f, d2); d2 = MFMA16(a1.f, bfr[2][1].f, d2);
      d3 = MFMA16(a0.f, bfr[3][0].f, d3); d3 = MFMA16(a1.f, bfr[3][1].f, d3);

      const float4 rt4 = *(const float4*)(Rl + ni * NN + st * 16 + q * 4);
      const float rte[4] = {rt4.x, rt4.y, rt4.z, rt4.w};
#pragma unroll
      for (int e = 0; e < 4; ++e) {
        ag0 = fmaf(rte[e], fmaxf(d0[e], 0.f), ag0);
        ag1 = fmaf(rte[e], fmaxf(d1[e], 0.f), ag1);
        ag2 = fmaf(rte[e], fmaxf(d2[e], 0.f), ag2);
        ag3 = fmaf(rte[e], fmaxf(d3[e], 0.f), ag3);
      }
    }
    ag0 += __shfl_xor(ag0, 16); ag0 += __shfl_xor(ag0, 32);
    ag1 += __shfl_xor(ag1, 16); ag1 += __shfl_xor(ag1, 32);
    ag2 += __shfl_xor(ag2, 16); ag2 += __shfl_xor(ag2, 32);
    ag3 += __shfl_xor(ag3, 16); ag3 += __shfl_xor(ag3, 32);
    const float val = (q == 0) ? ag0 : (q == 1) ? ag1 : (q == 2) ? ag2 : ag3;
    AggL[ni * 68 + lane] = val;  // o = q*16+r = lane
  }

  // ---- node-phase weights (independent of Agg: load before the barrier)
  const int o = w * 16 + r;     // this wave's output column, layers 1&2
  Frag B1[2], B2[2];
#pragma unroll
  for (int ks = 0; ks < 2; ++ks) {
    const float* p1 = out1_w + o * 68 + 4 + ks * 32 + q * 8;
    const float4 c0 = *(const float4*)p1;
    const float4 c1 = *(const float4*)(p1 + 4);
    B1[ks].u[0] = pk16(c0.x, c0.y); B1[ks].u[1] = pk16(c0.z, c0.w);
    B1[ks].u[2] = pk16(c1.x, c1.y); B1[ks].u[3] = pk16(c1.z, c1.w);
    const float* p2 = out2_w + o * 64 + ks * 32 + q * 8;
    const float4 e0 = *(const float4*)p2;
    const float4 e1 = *(const float4*)(p2 + 4);
    B2[ks].u[0] = pk16(e0.x, e0.y); B2[ks].u[1] = pk16(e0.z, e0.w);
    B2[ks].u[2] = pk16(e1.x, e1.y); B2[ks].u[3] = pk16(e1.z, e1.w);
  }
  const float4 w1x = *(const float4*)(out1_w + o * 68);  // x-part of layer 1
  const float b1o = out1_b[o];
  const float b2o = out2_b[o];
  __syncthreads();

  // ---------------- node phase ----------------
  // Layer 1: h1[n][o] = relu(b1[o] + x[n]·W1x[o] + agg[n]·W1k[o])
  {
    Frag A[2];
#pragma unroll
    for (int ks = 0; ks < 2; ++ks) {
      const float4 g0 = *(const float4*)(AggL + r * 68 + ks * 32 + q * 8);
      const float4 g1 = *(const float4*)(AggL + r * 68 + ks * 32 + q * 8 + 4);
      A[ks].u[0] = pk16(g0.x, g0.y); A[ks].u[1] = pk16(g0.z, g0.w);
      A[ks].u[2] = pk16(g1.x, g1.y); A[ks].u[3] = pk16(g1.z, g1.w);
    }
    f32x4 d = {b1o, b1o, b1o, b1o};
    d = MFMA16(A[0].f, B1[0].f, d);
    d = MFMA16(A[1].f, B1[1].f, d);
#pragma unroll
    for (int reg = 0; reg < 4; ++reg) {
      const int n = q * 4 + reg;
      const float4 x = Xl[n];
      const float hv = d[reg] + x.x * w1x.x + x.y * w1x.y + x.z * w1x.z + x.w * w1x.w;
      H1L[n * 68 + o] = fmaxf(hv, 0.f);
    }
  }
  __syncthreads();

  // Layer 2: h2 = relu(b2 + h1·W2^T)
  {
    Frag A[2];
#pragma unroll
    for (int ks = 0; ks < 2; ++ks) {
      const float4 g0 = *(const float4*)(H1L + r * 68 + ks * 32 + q * 8);
      const float4 g1 = *(const float4*)(H1L + r * 68 + ks * 32 + q * 8 + 4);
      A[ks].u[0] = pk16(g0.x, g0.y); A[ks].u[1] = pk16(g0.z, g0.w);
      A[ks].u[2] = pk16(g1.x, g1.y); A[ks].u[3] = pk16(g1.z, g1.w);
    }
    f32x4 d = {b2o, b2o, b2o, b2o};
    d = MFMA16(A[0].f, B2[0].f, d);
    d = MFMA16(A[1].f, B2[1].f, d);
#pragma unroll
    for (int reg = 0; reg < 4; ++reg) {
      const int n = q * 4 + reg;
      H2L[n * 68 + o] = fmaxf(d[reg], 0.f);
    }
  }
  __syncthreads();

  // Layer 3 (wave 0 only): delta[n][d] = b3[d] + h2[n]·W3[d]; out = x + delta
  if (w == 0) {
    Frag B3[2];
#pragma unroll
    for (int ks = 0; ks < 2; ++ks) {
      const float* p3 = out3_w + (r & 3) * 64 + ks * 32 + q * 8;
      float4 c0 = *(const float4*)p3;
      float4 c1 = *(const float4*)(p3 + 4);
      if (r >= 4) { c0 = make_float4(0, 0, 0, 0); c1 = make_float4(0, 0, 0, 0); }
      B3[ks].u[0] = pk16(c0.x, c0.y); B3[ks].u[1] = pk16(c0.z, c0.w);
      B3[ks].u[2] = pk16(c1.x, c1.y); B3[ks].u[3] = pk16(c1.z, c1.w);
    }
    Frag A[2];
#pragma unroll
    for (int ks = 0; ks < 2; ++ks) {
      const float4 g0 = *(const float4*)(H2L + r * 68 + ks * 32 + q * 8);
      const float4 g1 = *(const float4*)(H2L + r * 68 + ks * 32 + q * 8 + 4);
      A[ks].u[0] = pk16(g0.x, g0.y); A[ks].u[1] = pk16(g0.z, g0.w);
      A[ks].u[2] = pk16(g1.x, g1.y); A[ks].u[3] = pk16(g1.z, g1.w);
    }
    const float b3o = (r < 4) ? out3_b[r] : 0.f;
    f32x4 d = {b3o, b3o, b3o, b3o};
    d = MFMA16(A[0].f, B3[0].f, d);
    d = MFMA16(A[1].f, B3[1].f, d);
    if (r < 4) {
      const float* xf = (const float*)Xl;
#pragma unroll
      for (int reg = 0; reg < 4; ++reg) {
        const int n = q * 4 + reg;
        out[((b * NN + n_base + n) * NTO + t) * ND + r] = xf[n * 4 + r] + d[reg];
      }
    }
  }
}

extern "C" void kernel_launch(void* const* d_in, const int* in_sizes, int n_in,
                              void* d_out, int out_size, void* d_ws, size_t ws_size,
                              hipStream_t stream) {
  const float* inputs   = (const float*)d_in[0];
  const float* rel_type = (const float*)d_in[1];
  const float* fc1_w  = (const float*)d_in[4];
  const float* fc1_b  = (const float*)d_in[5];
  const float* fc2_w  = (const float*)d_in[6];
  const float* fc2_b  = (const float*)d_in[7];
  const float* out1_w = (const float*)d_in[8];
  const float* out1_b = (const float*)d_in[9];
  const float* out2_w = (const float*)d_in[10];
  const float* out2_b = (const float*)d_in[11];
  const float* out3_w = (const float*)d_in[12];
  const float* out3_b = (const float*)d_in[13];
  float* out = (float*)d_out;

  nri_fused_kernel<<<NB * NTO * 4, 256, 0, stream>>>(
      inputs, rel_type, fc1_w, fc1_b, fc2_w, fc2_b,
      out1_w, out1_b, out2_w, out2_b, out3_w, out3_b, out);
}